// Round 8
// baseline (310.367 us; speedup 1.0000x reference)
//
#include <hip/hip_runtime.h>

constexpr int NN  = 20000;   // nodes
constexpr int NE  = 160000;  // edges (= 625*256)
constexpr int CAP = 32;      // per-node bucket capacity (deg ~ Poisson(8), max ~21)
constexpr int TN2 = 8;       // node tile per block (fused kernels); 2500*8 == NN
constexpr int NBM = 16;      // blocks in MLP kernel

// ---- agent-scope (cross-XCD safe) scalar access --------------------------
__device__ inline void gstore(float* p, float v) {
    __hip_atomic_store(p, v, __ATOMIC_RELAXED, __HIP_MEMORY_SCOPE_AGENT);
}
__device__ inline float gload(const float* p) {
    return __hip_atomic_load(p, __ATOMIC_RELAXED, __HIP_MEMORY_SCOPE_AGENT);
}

// inter-block barrier: monotonic counter, arrive then (optionally) spin
__device__ inline void mbarrier(int* ctr, int target, bool wait) {
    __syncthreads();
    if (threadIdx.x == 0) {
        __threadfence();
        __hip_atomic_fetch_add(ctr, 1, __ATOMIC_ACQ_REL, __HIP_MEMORY_SCOPE_AGENT);
        if (wait)
            while (__hip_atomic_load(ctr, __ATOMIC_ACQUIRE, __HIP_MEMORY_SCOPE_AGENT) < target) {}
    }
    __syncthreads();
}

// ---------------------------------------------------------------------------
// Stage W columns [c0, c0+CH) into LDS. s<8 = We, s==8 = be, s==9 = root.
// ---------------------------------------------------------------------------
template<int FI, int FO2, int CH>
__device__ void stage_half(float* Wh, const float* __restrict__ We,
                           const float* __restrict__ be, const float* __restrict__ root,
                           int c0)
{
    constexpr int O4 = FO2 / 4;
    for (int t = threadIdx.x; t < FI * CH; t += 256) {
        const int f = t / CH, ccp = t % CH, cc = c0 + ccp;
        const int s = cc / O4, oq = cc % O4;
        const float4* src;
        if (s < 8)       src = (const float4*)(We + (size_t)s * FI * FO2 + f * FO2 + oq * 4);
        else if (s == 8) src = (const float4*)(be + f * FO2 + oq * 4);
        else             src = (const float4*)(root + f * FO2 + oq * 4);
        ((float4*)Wh)[t] = *src;
    }
}

// ---------------------------------------------------------------------------
// GEMM columns [c0,c0+CH): segs 0..8 -> P_lds (stride 9*FO2); seg9+bias -> g.
// ---------------------------------------------------------------------------
template<int FI, int FO2, int CH>
__device__ void gemm_PL(const float* htile, const float* Wh,
                        const float* __restrict__ bias,
                        float* P_lds, float* __restrict__ seg9g, int n0, int c0)
{
    constexpr int O4 = FO2 / 4, PL = 9 * FO2;
    constexpr int TPN = 256 / TN2;       // 32
    constexpr int HS  = FI + 4;
    const int nl = threadIdx.x / TPN, lane = threadIdx.x % TPN;
    const float*  hr = &htile[nl * HS];
    const float4* W4 = (const float4*)Wh;
    for (int ccp = lane; ccp < CH; ccp += TPN) {
        const int cc = c0 + ccp;
        float4 a = {0.f, 0.f, 0.f, 0.f};
        #pragma unroll
        for (int f = 0; f < FI; f++) {
            const float  hf = hr[f];
            const float4 w  = W4[f * CH + ccp];
            a.x = fmaf(hf, w.x, a.x); a.y = fmaf(hf, w.y, a.y);
            a.z = fmaf(hf, w.z, a.z); a.w = fmaf(hf, w.w, a.w);
        }
        if (cc < 9 * O4) {
            *(float4*)&P_lds[nl * PL + cc * 4] = a;
        } else {
            const float4 b4 = ((const float4*)bias)[cc - 9 * O4];
            a.x += b4.x; a.y += b4.y; a.z += b4.z; a.w += b4.w;
            *(float4*)&seg9g[(size_t)(n0 + nl) * FO2 + (cc - 9 * O4) * 4] = a;
        }
    }
}

// ---------------------------------------------------------------------------
// Push phase (reads LDS P, e-rows from esort in slot order — mostly seq).
// scratch (overlaid on dead W region): elds 2048f | esl 256i | enl 256i.
// Caller guarantees a barrier before entry (W dead) and offs_s ready.
// ---------------------------------------------------------------------------
template<int FO2>
__device__ void push_phase(const float* P_lds, const int* offs_s,
                           const float* __restrict__ esort, float* __restrict__ msg,
                           float* scratch, int n0)
{
    constexpr int PL = 9 * FO2, OQ2 = FO2 / 4;
    float* elds = scratch;
    int*   esl  = (int*)(scratch + 2048);
    int*   enl  = esl + 256;
    const int tid = threadIdx.x;
    const int ET = offs_s[TN2];
    for (int T = tid; T < ET; T += 256) {
        int nl = 0;
        #pragma unroll
        for (int i = 1; i < TN2; i++) nl += (T >= offs_s[i]);
        const int j    = T - offs_s[nl];
        const int slot = (n0 + nl) * CAP + j;
        esl[T] = slot; enl[T] = nl;
        *(float4*)&elds[T * 8]     = *(const float4*)(esort + (size_t)slot * 8);
        *(float4*)&elds[T * 8 + 4] = *(const float4*)(esort + (size_t)slot * 8 + 4);
    }
    __syncthreads();
    for (int T = tid; T < ET * OQ2; T += 256) {
        const int ed = T / OQ2, oq = T % OQ2;
        const int nl = enl[ed], slot = esl[ed];
        const float* Pr = &P_lds[nl * PL + oq * 4];
        const float* ee = &elds[ed * 8];
        float4 m = *(const float4*)(Pr + 8 * FO2);
        #pragma unroll
        for (int s = 0; s < 8; s++) {
            const float  es = ee[s];
            const float4 w  = *(const float4*)(Pr + s * FO2);
            m.x = fmaf(es, w.x, m.x); m.y = fmaf(es, w.y, m.y);
            m.z = fmaf(es, w.z, m.z); m.w = fmaf(es, w.w, m.w);
        }
        *(float4*)&msg[(size_t)slot * FO2 + oq * 4] = m;
    }
}

// ---------------------------------------------------------------------------
// D2: dual buckets. src bucket gets e-row materialized in slot order (esort);
// tgt bucket records the src slot for gather indirection.
// ---------------------------------------------------------------------------
__global__ __launch_bounds__(256)
void bucket_kernel(const int* __restrict__ eidx, const float* __restrict__ e,
                   int* __restrict__ cnt_s, int* __restrict__ cnt_t,
                   int* __restrict__ te_slot, float* __restrict__ esort)
{
    const int eid = blockIdx.x * 256 + threadIdx.x;    // NE == 625*256
    const int2 st = ((const int2*)eidx)[eid];
    const int qs = atomicAdd(&cnt_s[st.x], 1);
    if (qs < CAP) {
        const int slot = st.x * CAP + qs;
        const float4* e4 = (const float4*)(e + (size_t)eid * 8);
        *(float4*)&esort[(size_t)slot * 8]     = e4[0];
        *(float4*)&esort[(size_t)slot * 8 + 4] = e4[1];
        const int qt = atomicAdd(&cnt_t[st.y], 1);
        if (qt < CAP) te_slot[st.y * CAP + qt] = slot;
    }
}

// ---------------------------------------------------------------------------
// D3: layer 1 — x tile -> P1(LDS segs0..8, seg9->global) -> msg1.
// FI=16, FO2=40, two W passes (CH=50). LDS ~26 KB.
// ---------------------------------------------------------------------------
__global__ __launch_bounds__(256, 6)
void l1_push_kernel(const float* __restrict__ x,
                    const float* __restrict__ We1, const float* __restrict__ be1,
                    const float* __restrict__ root1, const float* __restrict__ b1,
                    const int* __restrict__ cnt_s, const float* __restrict__ esort,
                    float* __restrict__ seg9_1, float* __restrict__ msg1)
{
    constexpr int FI = 16, FO2 = 40, CH = 50;
    constexpr int WHF = FI * CH * 4;        // 3200
    constexpr int PLF = TN2 * 9 * FO2;      // 2880
    constexpr int HTF = TN2 * (FI + 4);     // 160
    __shared__ float smem[WHF + PLF + HTF];
    __shared__ int offs_s[TN2 + 1];
    float* Wh    = smem;
    float* P_lds = smem + WHF;
    float* htile = smem + WHF + PLF;
    const int tid = threadIdx.x;
    const int n0  = blockIdx.x * TN2;

    if (tid == 0) {
        int a = 0;
        for (int i = 0; i < TN2; i++) { offs_s[i] = a; a += min(cnt_s[n0 + i], CAP); }
        offs_s[TN2] = a;
    }
    stage_half<FI, FO2, CH>(Wh, We1, be1, root1, 0);
    for (int t = tid; t < TN2 * 4; t += 256) {
        const int nl = t / 4, fq = t % 4;
        *(float4*)&htile[nl * 20 + fq * 4] =
            *(const float4*)(x + (size_t)(n0 + nl) * 16 + fq * 4);
    }
    __syncthreads();
    gemm_PL<FI, FO2, CH>(htile, Wh, b1, P_lds, seg9_1, n0, 0);
    __syncthreads();
    stage_half<FI, FO2, CH>(Wh, We1, be1, root1, CH);
    __syncthreads();
    gemm_PL<FI, FO2, CH>(htile, Wh, b1, P_lds, seg9_1, n0, CH);
    __syncthreads();
    push_phase<FO2>(P_lds, offs_s, esort, msg1, Wh, n0);
}

// ---------------------------------------------------------------------------
// D4/D5: fused gather(edge-parallel) -> relu -> GEMM -> push.
// CHP = W columns per pass (30 => 2 passes for FI=40; 60 => 1 pass FI=24).
// ---------------------------------------------------------------------------
template<int FI, int FO2, int CHP>
__global__ __launch_bounds__(256, 6)
void gather_gemm_push_kernel(const float* __restrict__ msg_prev,
                             const int* __restrict__ cnt_t, const int* __restrict__ te_slot,
                             const float* __restrict__ seg9_prev,
                             const float* __restrict__ We, const float* __restrict__ be,
                             const float* __restrict__ root, const float* __restrict__ bias,
                             const int* __restrict__ cnt_s, const float* __restrict__ esort,
                             float* __restrict__ seg9_next, float* __restrict__ msg_next)
{
    constexpr int C4    = 10 * FO2 / 4;
    constexpr int NPASS = C4 / CHP;
    constexpr int OQi   = FI / 4, HS = FI + 4;
    constexpr int WHF   = FI * CHP * 4;
    constexpr int PLF   = TN2 * 9 * FO2;
    constexpr int HTF   = TN2 * HS;
    __shared__ float smem[WHF + PLF + HTF];
    __shared__ int tslot[TN2 * CAP];
    __shared__ int offs_t[TN2 + 1], offs_s[TN2 + 1];
    float* Wh    = smem;
    float* P_lds = smem + WHF;
    float* htile = smem + WHF + PLF;
    const int tid = threadIdx.x;
    const int n0  = blockIdx.x * TN2;

    if (tid == 0) {
        int a = 0;
        for (int i = 0; i < TN2; i++) { offs_t[i] = a; a += min(cnt_t[n0 + i], CAP); }
        offs_t[TN2] = a;
    }
    if (tid == 64) {
        int a = 0;
        for (int i = 0; i < TN2; i++) { offs_s[i] = a; a += min(cnt_s[n0 + i], CAP); }
        offs_s[TN2] = a;
    }
    for (int t = tid; t < TN2 * CAP; t += 256) tslot[t] = te_slot[n0 * CAP + t];
    stage_half<FI, FO2, CHP>(Wh, We, be, root, 0);
    for (int t = tid; t < TN2 * OQi; t += 256) {
        const int nl = t / OQi, oq = t % OQi;
        *(float4*)&htile[nl * HS + oq * 4] =
            *(const float4*)(seg9_prev + (size_t)(n0 + nl) * FI + oq * 4);
    }
    __syncthreads();

    // gather: one item per (edge, channel-quad); single independent load each
    const int ETt = offs_t[TN2];
    for (int T = tid; T < ETt * OQi; T += 256) {
        const int ed = T / OQi, oq = T % OQi;
        int nl = 0;
        #pragma unroll
        for (int i = 1; i < TN2; i++) nl += (ed >= offs_t[i]);
        const int k    = ed - offs_t[nl];
        const int slot = tslot[nl * CAP + k];
        const float4 v = *(const float4*)(msg_prev + (size_t)slot * FI + oq * 4);
        float* hp = &htile[nl * HS + oq * 4];
        atomicAdd(hp + 0, v.x);
        atomicAdd(hp + 1, v.y);
        atomicAdd(hp + 2, v.z);
        atomicAdd(hp + 3, v.w);
    }
    __syncthreads();
    for (int t = tid; t < TN2 * OQi; t += 256) {
        float4* p = (float4*)&htile[(t / OQi) * HS + (t % OQi) * 4];
        float4 v = *p;
        v.x = fmaxf(v.x, 0.f); v.y = fmaxf(v.y, 0.f);
        v.z = fmaxf(v.z, 0.f); v.w = fmaxf(v.w, 0.f);
        *p = v;
    }
    __syncthreads();

    #pragma unroll
    for (int p = 0; p < NPASS; p++) {
        if (p > 0) {
            __syncthreads();
            stage_half<FI, FO2, CHP>(Wh, We, be, root, p * CHP);
            __syncthreads();
        }
        gemm_PL<FI, FO2, CHP>(htile, Wh, bias, P_lds, seg9_next, n0, p * CHP);
    }
    __syncthreads();
    push_phase<FO2>(P_lds, offs_s, esort, msg_next, Wh, n0);
}

// ---------------------------------------------------------------------------
// D6: edge-parallel gather of msg3 + seg9_3, relu, colsum -> g (24-wide).
// ---------------------------------------------------------------------------
__global__ __launch_bounds__(256)
void msg_colsum_kernel(const float* __restrict__ msg, const int* __restrict__ cnt_t,
                       const int* __restrict__ te_slot, const float* __restrict__ seg9,
                       float* __restrict__ g)
{
    constexpr int FO = 24, OQ = 6, HS = 28;
    __shared__ float htile[TN2 * HS];
    __shared__ int tslot[TN2 * CAP];
    __shared__ int offs_t[TN2 + 1];
    __shared__ float gl[FO];
    const int tid = threadIdx.x;
    const int n0  = blockIdx.x * TN2;

    if (tid == 0) {
        int a = 0;
        for (int i = 0; i < TN2; i++) { offs_t[i] = a; a += min(cnt_t[n0 + i], CAP); }
        offs_t[TN2] = a;
    }
    if (tid >= 64 && tid < 64 + FO) gl[tid - 64] = 0.f;
    for (int t = tid; t < TN2 * CAP; t += 256) tslot[t] = te_slot[n0 * CAP + t];
    for (int t = tid; t < TN2 * OQ; t += 256) {
        const int nl = t / OQ, oq = t % OQ;
        *(float4*)&htile[nl * HS + oq * 4] =
            *(const float4*)(seg9 + (size_t)(n0 + nl) * FO + oq * 4);
    }
    __syncthreads();

    const int ETt = offs_t[TN2];
    for (int T = tid; T < ETt * OQ; T += 256) {
        const int ed = T / OQ, oq = T % OQ;
        int nl = 0;
        #pragma unroll
        for (int i = 1; i < TN2; i++) nl += (ed >= offs_t[i]);
        const int k    = ed - offs_t[nl];
        const int slot = tslot[nl * CAP + k];
        const float4 v = *(const float4*)(msg + (size_t)slot * FO + oq * 4);
        float* hp = &htile[nl * HS + oq * 4];
        atomicAdd(hp + 0, v.x);
        atomicAdd(hp + 1, v.y);
        atomicAdd(hp + 2, v.z);
        atomicAdd(hp + 3, v.w);
    }
    __syncthreads();
    for (int t = tid; t < TN2 * FO; t += 256) {
        const int nl = t / FO, o = t % FO;
        atomicAdd(&gl[o], fmaxf(htile[nl * HS + o], 0.f));
    }
    __syncthreads();
    if (tid < FO) unsafeAtomicAdd(&g[tid], gl[tid]);
}

// ---------------------------------------------------------------------------
// D7: MLP head, 16 blocks, 2 inter-block barriers.
// ---------------------------------------------------------------------------
__global__ __launch_bounds__(256)
void mlp_kernel(const float* __restrict__ g, int* __restrict__ ctr,
                const float* __restrict__ Wd1, const float* __restrict__ bd1,
                const float* __restrict__ Wd2, const float* __restrict__ bd2,
                const float* __restrict__ Wd3, const float* __restrict__ bd3,
                const float* __restrict__ Wd4, const float* __restrict__ bd4,
                const float* __restrict__ Wd5, const float* __restrict__ bd5,
                const float* __restrict__ Wd6, const float* __restrict__ bd6,
                float* __restrict__ m3, float* __restrict__ m4,
                float* __restrict__ out)
{
    __shared__ float v0[768];
    __shared__ float v1[96];
    __shared__ float red[256];
    const int tid = threadIdx.x, b = blockIdx.x;

    if (tid < 24) v0[tid] = g[tid];
    __syncthreads();
    if (tid < 96) {
        float a = bd1[tid];
        #pragma unroll
        for (int i = 0; i < 24; i++) a = fmaf(v0[i], Wd1[i * 96 + tid], a);
        v1[tid] = fmaxf(a, 0.f);
    }
    __syncthreads();
    {
        float a = bd2[tid];
        #pragma unroll
        for (int i = 0; i < 96; i++) a = fmaf(v1[i], Wd2[i * 256 + tid], a);
        red[tid] = fmaxf(a, 0.f);
    }
    __syncthreads();
    v0[tid] = red[tid];
    __syncthreads();

    if (tid < 192) {
        const int o = b * 48 + (tid % 48), kg = tid / 48;
        float a = 0.f;
        #pragma unroll 8
        for (int i = kg * 64; i < kg * 64 + 64; i++)
            a = fmaf(v0[i], Wd3[(size_t)i * 768 + o], a);
        red[tid] = a;
    }
    __syncthreads();
    if (tid < 48) {
        float s = bd3[b * 48 + tid] + red[tid] + red[48 + tid] + red[96 + tid] + red[144 + tid];
        gstore(&m3[b * 48 + tid], fmaxf(s, 0.f));
    }
    mbarrier(ctr, 1 * NBM, true);

    for (int i = tid; i < 768; i += 256) v0[i] = gload(&m3[i]);
    __syncthreads();
    {
        const int o = b * 32 + (tid & 31), kg = tid >> 5;
        float a = 0.f;
        #pragma unroll 8
        for (int i = kg * 96; i < kg * 96 + 96; i++)
            a = fmaf(v0[i], Wd4[(size_t)i * 512 + o], a);
        red[tid] = a;
    }
    __syncthreads();
    if (tid < 32) {
        float s = bd4[b * 32 + tid];
        #pragma unroll
        for (int k = 0; k < 8; k++) s += red[k * 32 + tid];
        gstore(&m4[b * 32 + tid], fmaxf(s, 0.f));
    }
    mbarrier(ctr, 2 * NBM, b == 0);

    if (b == 0) {
        for (int i = tid; i < 512; i += 256) v0[i] = gload(&m4[i]);
        __syncthreads();
        {
            const int o = tid & 63, kg = tid >> 6;
            float a = 0.f;
            #pragma unroll 8
            for (int i = kg * 128; i < kg * 128 + 128; i++)
                a = fmaf(v0[i], Wd5[(size_t)i * 64 + o], a);
            red[tid] = a;
        }
        __syncthreads();
        if (tid < 64) {
            float s = bd5[tid] + red[tid] + red[64 + tid] + red[128 + tid] + red[192 + tid];
            float v = fmaxf(s, 0.f) * Wd6[tid];
            #pragma unroll
            for (int off = 32; off > 0; off >>= 1)
                v += __shfl_down(v, off, 64);
            if (tid == 0) out[0] = v + bd6[0];
        }
    }
}

// ---------------------------------------------------------------------------
extern "C" void kernel_launch(void* const* d_in, const int* in_sizes, int n_in,
                              void* d_out, int out_size, void* d_ws, size_t ws_size,
                              hipStream_t stream)
{
    const float* x     = (const float*)d_in[0];
    const int*   eidx  = (const int*)  d_in[1];
    const float* e     = (const float*)d_in[2];
    const float* We1   = (const float*)d_in[3];  const float* be1 = (const float*)d_in[4];
    const float* root1 = (const float*)d_in[5];  const float* b1  = (const float*)d_in[6];
    const float* We2   = (const float*)d_in[7];  const float* be2 = (const float*)d_in[8];
    const float* root2 = (const float*)d_in[9];  const float* b2  = (const float*)d_in[10];
    const float* We3   = (const float*)d_in[11]; const float* be3 = (const float*)d_in[12];
    const float* root3 = (const float*)d_in[13]; const float* b3  = (const float*)d_in[14];
    const float* Wd1 = (const float*)d_in[15]; const float* bd1 = (const float*)d_in[16];
    const float* Wd2 = (const float*)d_in[17]; const float* bd2 = (const float*)d_in[18];
    const float* Wd3 = (const float*)d_in[19]; const float* bd3 = (const float*)d_in[20];
    const float* Wd4 = (const float*)d_in[21]; const float* bd4 = (const float*)d_in[22];
    const float* Wd5 = (const float*)d_in[23]; const float* bd5 = (const float*)d_in[24];
    const float* Wd6 = (const float*)d_in[25]; const float* bd6 = (const float*)d_in[26];

    // ---- workspace layout (4-byte units) ----
    int*   wi      = (int*)d_ws;
    float* wf      = (float*)d_ws;
    int*   cnt_s   = wi;                       //         0 ..    20000
    int*   cnt_t   = wi + 20000;               //     20000 ..    40000
    float* g       = wf + 40000;               //     24
    int*   mctr    = wi + 40064;               //     own 64B line
    float* m3      = wf + 40096;               //     768
    float* m4      = m3 + 768;                 //     512   (ends 41376)
    int*   te_slot = wi + 41376;               //     640,000 ->   681,376
    float* esort   = wf + 681376;              //     640,000*8 = 5,120,000 -> 5,801,376
    float* seg9_1  = wf + 5801376;             //     800,000 -> 6,601,376
    float* seg9_2  = wf + 6601376;             //     480,000 -> 7,081,376
    float* seg9_3  = wf + 7081376;             //     480,000 -> 7,561,376
    float* msg1    = wf + 7561376;             //     25,600,000 -> 33,161,376
    float* msg3    = msg1;                     //     msg1 dead before msg3 written
    float* msg2    = wf + 33161376;            //     15,360,000 -> 48,521,376
    // total ~48.5M floats ~= 194 MB

    // D1: zero cnt_s + cnt_t + g + mctr + m3/m4 (165 KB)
    hipMemsetAsync(d_ws, 0, (size_t)41376 * sizeof(float), stream);

    // D2: dual buckets + esort (e rows in src-slot order)
    bucket_kernel<<<625, 256, 0, stream>>>(eidx, e, cnt_s, cnt_t, te_slot, esort);

    // D3: layer 1 — x -> P1(LDS) -> msg1 + seg9_1
    l1_push_kernel<<<NN / TN2, 256, 0, stream>>>(x, We1, be1, root1, b1,
                                                 cnt_s, esort, seg9_1, msg1);

    // D4: gather msg1 -> h1 -> P2(LDS) -> msg2 + seg9_2   (2 W passes)
    gather_gemm_push_kernel<40, 24, 30><<<NN / TN2, 256, 0, stream>>>(
        msg1, cnt_t, te_slot, seg9_1, We2, be2, root2, b2,
        cnt_s, esort, seg9_2, msg2);

    // D5: gather msg2 -> h2 -> P3(LDS) -> msg3 + seg9_3   (1 W pass)
    gather_gemm_push_kernel<24, 24, 60><<<NN / TN2, 256, 0, stream>>>(
        msg2, cnt_t, te_slot, seg9_2, We3, be3, root3, b3,
        cnt_s, esort, seg9_3, msg3);

    // D6: g = colsum(relu(msg3-sum + seg9_3))
    msg_colsum_kernel<<<NN / TN2, 256, 0, stream>>>(msg3, cnt_t, te_slot, seg9_3, g);

    // D7: MLP head (16 blocks, 2 internal barriers)
    mlp_kernel<<<NBM, 256, 0, stream>>>(g, mctr,
                                        Wd1, bd1, Wd2, bd2, Wd3, bd3,
                                        Wd4, bd4, Wd5, bd5, Wd6, bd6,
                                        m3, m4, (float*)d_out);
}

// Round 9
// 254.905 us; speedup vs baseline: 1.2176x; 1.2176x over previous
//
#include <hip/hip_runtime.h>

constexpr int NN  = 20000;   // nodes
constexpr int NE  = 160000;  // edges (= 625*256)
constexpr int CAP = 32;      // per-node bucket capacity (deg ~ Poisson(8), max ~21)
constexpr int TN2 = 8;       // node tile per block (fused kernels); 2500*8 == NN
constexpr int NBM = 16;      // blocks in MLP kernel

// ---- agent-scope (cross-XCD safe) scalar access --------------------------
__device__ inline void gstore(float* p, float v) {
    __hip_atomic_store(p, v, __ATOMIC_RELAXED, __HIP_MEMORY_SCOPE_AGENT);
}
__device__ inline float gload(const float* p) {
    return __hip_atomic_load(p, __ATOMIC_RELAXED, __HIP_MEMORY_SCOPE_AGENT);
}

// inter-block barrier: monotonic counter, arrive then (optionally) spin
__device__ inline void mbarrier(int* ctr, int target, bool wait) {
    __syncthreads();
    if (threadIdx.x == 0) {
        __threadfence();
        __hip_atomic_fetch_add(ctr, 1, __ATOMIC_ACQ_REL, __HIP_MEMORY_SCOPE_AGENT);
        if (wait)
            while (__hip_atomic_load(ctr, __ATOMIC_ACQUIRE, __HIP_MEMORY_SCOPE_AGENT) < target) {}
    }
    __syncthreads();
}

// ---------------------------------------------------------------------------
// Stage W columns [c0, c0+CH) into LDS. s<8 = We, s==8 = be, s==9 = root.
// ---------------------------------------------------------------------------
template<int FI, int FO2, int CH>
__device__ void stage_half(float* Wh, const float* __restrict__ We,
                           const float* __restrict__ be, const float* __restrict__ root,
                           int c0)
{
    constexpr int O4 = FO2 / 4;
    for (int t = threadIdx.x; t < FI * CH; t += 256) {
        const int f = t / CH, ccp = t % CH, cc = c0 + ccp;
        const int s = cc / O4, oq = cc % O4;
        const float4* src;
        if (s < 8)       src = (const float4*)(We + (size_t)s * FI * FO2 + f * FO2 + oq * 4);
        else if (s == 8) src = (const float4*)(be + f * FO2 + oq * 4);
        else             src = (const float4*)(root + f * FO2 + oq * 4);
        ((float4*)Wh)[t] = *src;
    }
}

// ---------------------------------------------------------------------------
// GEMM columns [c0,c0+CH): segs 0..8 -> P_lds (stride 9*FO2); seg9+bias -> g.
// ---------------------------------------------------------------------------
template<int FI, int FO2, int CH>
__device__ void gemm_PL(const float* htile, const float* Wh,
                        const float* __restrict__ bias,
                        float* P_lds, float* __restrict__ seg9g, int n0, int c0)
{
    constexpr int O4 = FO2 / 4, PL = 9 * FO2;
    constexpr int TPN = 256 / TN2;       // 32
    constexpr int HS  = FI + 4;
    const int nl = threadIdx.x / TPN, lane = threadIdx.x % TPN;
    const float*  hr = &htile[nl * HS];
    const float4* W4 = (const float4*)Wh;
    for (int ccp = lane; ccp < CH; ccp += TPN) {
        const int cc = c0 + ccp;
        float4 a = {0.f, 0.f, 0.f, 0.f};
        #pragma unroll
        for (int f = 0; f < FI; f++) {
            const float  hf = hr[f];
            const float4 w  = W4[f * CH + ccp];
            a.x = fmaf(hf, w.x, a.x); a.y = fmaf(hf, w.y, a.y);
            a.z = fmaf(hf, w.z, a.z); a.w = fmaf(hf, w.w, a.w);
        }
        if (cc < 9 * O4) {
            *(float4*)&P_lds[nl * PL + cc * 4] = a;
        } else {
            const float4 b4 = ((const float4*)bias)[cc - 9 * O4];
            a.x += b4.x; a.y += b4.y; a.z += b4.z; a.w += b4.w;
            *(float4*)&seg9g[(size_t)(n0 + nl) * FO2 + (cc - 9 * O4) * 4] = a;
        }
    }
}

// ---------------------------------------------------------------------------
// Push phase (reads LDS P, e-rows from esort in slot order — mostly seq).
// scratch (overlaid on dead W region): elds 2048f | esl 256i | enl 256i.
// Caller guarantees a barrier before entry (W dead) and offs_s ready.
// ---------------------------------------------------------------------------
template<int FO2>
__device__ void push_phase(const float* P_lds, const int* offs_s,
                           const float* __restrict__ esort, float* __restrict__ msg,
                           float* scratch, int n0)
{
    constexpr int PL = 9 * FO2, OQ2 = FO2 / 4;
    float* elds = scratch;
    int*   esl  = (int*)(scratch + 2048);
    int*   enl  = esl + 256;
    const int tid = threadIdx.x;
    const int ET = offs_s[TN2];
    for (int T = tid; T < ET; T += 256) {
        int nl = 0;
        #pragma unroll
        for (int i = 1; i < TN2; i++) nl += (T >= offs_s[i]);
        const int j    = T - offs_s[nl];
        const int slot = (n0 + nl) * CAP + j;
        esl[T] = slot; enl[T] = nl;
        *(float4*)&elds[T * 8]     = *(const float4*)(esort + (size_t)slot * 8);
        *(float4*)&elds[T * 8 + 4] = *(const float4*)(esort + (size_t)slot * 8 + 4);
    }
    __syncthreads();
    for (int T = tid; T < ET * OQ2; T += 256) {
        const int ed = T / OQ2, oq = T % OQ2;
        const int nl = enl[ed], slot = esl[ed];
        const float* Pr = &P_lds[nl * PL + oq * 4];
        const float* ee = &elds[ed * 8];
        float4 m = *(const float4*)(Pr + 8 * FO2);
        #pragma unroll
        for (int s = 0; s < 8; s++) {
            const float  es = ee[s];
            const float4 w  = *(const float4*)(Pr + s * FO2);
            m.x = fmaf(es, w.x, m.x); m.y = fmaf(es, w.y, m.y);
            m.z = fmaf(es, w.z, m.z); m.w = fmaf(es, w.w, m.w);
        }
        *(float4*)&msg[(size_t)slot * FO2 + oq * 4] = m;
    }
}

// ---------------------------------------------------------------------------
// D2: dual buckets. src bucket gets e-row materialized in slot order (esort);
// tgt bucket records the src slot for gather indirection.
// ---------------------------------------------------------------------------
__global__ __launch_bounds__(256)
void bucket_kernel(const int* __restrict__ eidx, const float* __restrict__ e,
                   int* __restrict__ cnt_s, int* __restrict__ cnt_t,
                   int* __restrict__ te_slot, float* __restrict__ esort)
{
    const int eid = blockIdx.x * 256 + threadIdx.x;    // NE == 625*256
    const int2 st = ((const int2*)eidx)[eid];
    const int qs = atomicAdd(&cnt_s[st.x], 1);
    if (qs < CAP) {
        const int slot = st.x * CAP + qs;
        const float4* e4 = (const float4*)(e + (size_t)eid * 8);
        *(float4*)&esort[(size_t)slot * 8]     = e4[0];
        *(float4*)&esort[(size_t)slot * 8 + 4] = e4[1];
        const int qt = atomicAdd(&cnt_t[st.y], 1);
        if (qt < CAP) te_slot[st.y * CAP + qt] = slot;
    }
}

// ---------------------------------------------------------------------------
// D3: layer 1 — x tile -> P1(LDS segs0..8, seg9->global) -> msg1.
// FI=16, FO2=40, two W passes (CH=50). LDS ~25 KB.
// ---------------------------------------------------------------------------
__global__ __launch_bounds__(256, 4)
void l1_push_kernel(const float* __restrict__ x,
                    const float* __restrict__ We1, const float* __restrict__ be1,
                    const float* __restrict__ root1, const float* __restrict__ b1,
                    const int* __restrict__ cnt_s, const float* __restrict__ esort,
                    float* __restrict__ seg9_1, float* __restrict__ msg1)
{
    constexpr int FI = 16, FO2 = 40, CH = 50;
    constexpr int WHF = FI * CH * 4;        // 3200
    constexpr int PLF = TN2 * 9 * FO2;      // 2880
    constexpr int HTF = TN2 * (FI + 4);     // 160
    __shared__ float smem[WHF + PLF + HTF];
    __shared__ int offs_s[TN2 + 1];
    float* Wh    = smem;
    float* P_lds = smem + WHF;
    float* htile = smem + WHF + PLF;
    const int tid = threadIdx.x;
    const int n0  = blockIdx.x * TN2;

    if (tid == 0) {
        int a = 0;
        for (int i = 0; i < TN2; i++) { offs_s[i] = a; a += min(cnt_s[n0 + i], CAP); }
        offs_s[TN2] = a;
    }
    stage_half<FI, FO2, CH>(Wh, We1, be1, root1, 0);
    for (int t = tid; t < TN2 * 4; t += 256) {
        const int nl = t / 4, fq = t % 4;
        *(float4*)&htile[nl * 20 + fq * 4] =
            *(const float4*)(x + (size_t)(n0 + nl) * 16 + fq * 4);
    }
    __syncthreads();
    gemm_PL<FI, FO2, CH>(htile, Wh, b1, P_lds, seg9_1, n0, 0);
    __syncthreads();
    stage_half<FI, FO2, CH>(Wh, We1, be1, root1, CH);
    __syncthreads();
    gemm_PL<FI, FO2, CH>(htile, Wh, b1, P_lds, seg9_1, n0, CH);
    __syncthreads();
    push_phase<FO2>(P_lds, offs_s, esort, msg1, Wh, n0);
}

// ---------------------------------------------------------------------------
// D4/D5: fused gather (deep-batched, one thread per (node,oq)) -> relu
// -> GEMM -> push. 8 independent dwordx4 loads in flight per thread.
// ---------------------------------------------------------------------------
template<int FI, int FO2, int CHP>
__global__ __launch_bounds__(256, 4)
void gather_gemm_push_kernel(const float* __restrict__ msg_prev,
                             const int* __restrict__ cnt_t, const int* __restrict__ te_slot,
                             const float* __restrict__ seg9_prev,
                             const float* __restrict__ We, const float* __restrict__ be,
                             const float* __restrict__ root, const float* __restrict__ bias,
                             const int* __restrict__ cnt_s, const float* __restrict__ esort,
                             float* __restrict__ seg9_next, float* __restrict__ msg_next)
{
    constexpr int C4    = 10 * FO2 / 4;
    constexpr int NPASS = C4 / CHP;
    constexpr int OQi   = FI / 4, HS = FI + 4;
    constexpr int WHF   = FI * CHP * 4;
    constexpr int PLF   = TN2 * 9 * FO2;
    constexpr int HTF   = TN2 * HS;
    __shared__ float smem[WHF + PLF + HTF];
    __shared__ int tslot[TN2 * CAP];
    __shared__ int offs_s[TN2 + 1];
    float* Wh    = smem;
    float* P_lds = smem + WHF;
    float* htile = smem + WHF + PLF;
    const int tid = threadIdx.x;
    const int n0  = blockIdx.x * TN2;

    if (tid == 0) {
        int a = 0;
        for (int i = 0; i < TN2; i++) { offs_s[i] = a; a += min(cnt_s[n0 + i], CAP); }
        offs_s[TN2] = a;
    }
    // stage target-slot list, padded with -1 beyond each node's degree
    for (int t = tid; t < TN2 * CAP; t += 256) {
        const int nl = t / CAP, k = t % CAP;
        const int dd = min(cnt_t[n0 + nl], CAP);
        tslot[t] = (k < dd) ? te_slot[n0 * CAP + t] : -1;
    }
    stage_half<FI, FO2, CHP>(Wh, We, be, root, 0);
    for (int t = tid; t < TN2 * OQi; t += 256) {
        const int nl = t / OQi, oq = t % OQi;
        *(float4*)&htile[nl * HS + oq * 4] =
            *(const float4*)(seg9_prev + (size_t)(n0 + nl) * FI + oq * 4);
    }
    __syncthreads();

    // deep-batched gather: each thread owns one (node, oq); 8 loads in flight
    for (int T = tid; T < TN2 * OQi; T += 256) {
        const int nl = T / OQi, oq = T % OQi;
        const int d = min(cnt_t[n0 + nl], CAP);
        float4 acc = *(float4*)&htile[nl * HS + oq * 4];
        const int* ts = &tslot[nl * CAP];
        for (int k0 = 0; k0 < CAP; k0 += 8) {
            if (k0 >= d) break;
            int sl[8]; float4 v[8];
            #pragma unroll
            for (int u = 0; u < 8; u++) {
                sl[u] = ts[k0 + u];
                const int sc = sl[u] < 0 ? 0 : sl[u];
                v[u] = *(const float4*)(msg_prev + (size_t)sc * FI + oq * 4);
            }
            #pragma unroll
            for (int u = 0; u < 8; u++) {
                if (sl[u] >= 0) {
                    acc.x += v[u].x; acc.y += v[u].y;
                    acc.z += v[u].z; acc.w += v[u].w;
                }
            }
        }
        acc.x = fmaxf(acc.x, 0.f); acc.y = fmaxf(acc.y, 0.f);
        acc.z = fmaxf(acc.z, 0.f); acc.w = fmaxf(acc.w, 0.f);
        *(float4*)&htile[nl * HS + oq * 4] = acc;
    }
    __syncthreads();

    #pragma unroll
    for (int p = 0; p < NPASS; p++) {
        if (p > 0) {
            __syncthreads();
            stage_half<FI, FO2, CHP>(Wh, We, be, root, p * CHP);
            __syncthreads();
        }
        gemm_PL<FI, FO2, CHP>(htile, Wh, bias, P_lds, seg9_next, n0, p * CHP);
    }
    __syncthreads();
    push_phase<FO2>(P_lds, offs_s, esort, msg_next, Wh, n0);
}

// ---------------------------------------------------------------------------
// D6: deep-batched gather of msg3 + seg9_3, relu, colsum -> g (24-wide).
// ---------------------------------------------------------------------------
__global__ __launch_bounds__(256)
void msg_colsum_kernel(const float* __restrict__ msg, const int* __restrict__ cnt_t,
                       const int* __restrict__ te_slot, const float* __restrict__ seg9,
                       float* __restrict__ g)
{
    constexpr int FO = 24, OQ = 6;
    __shared__ int tslot[TN2 * CAP];
    __shared__ float gl[FO];
    const int tid = threadIdx.x;
    const int n0  = blockIdx.x * TN2;

    if (tid < FO) gl[tid] = 0.f;
    for (int t = tid; t < TN2 * CAP; t += 256) {
        const int nl = t / CAP, k = t % CAP;
        const int dd = min(cnt_t[n0 + nl], CAP);
        tslot[t] = (k < dd) ? te_slot[n0 * CAP + t] : -1;
    }
    __syncthreads();

    for (int T = tid; T < TN2 * OQ; T += 256) {
        const int nl = T / OQ, oq = T % OQ;
        const int d = min(cnt_t[n0 + nl], CAP);
        float4 acc = *(const float4*)(seg9 + (size_t)(n0 + nl) * FO + oq * 4);
        const int* ts = &tslot[nl * CAP];
        for (int k0 = 0; k0 < CAP; k0 += 8) {
            if (k0 >= d) break;
            int sl[8]; float4 v[8];
            #pragma unroll
            for (int u = 0; u < 8; u++) {
                sl[u] = ts[k0 + u];
                const int sc = sl[u] < 0 ? 0 : sl[u];
                v[u] = *(const float4*)(msg + (size_t)sc * FO + oq * 4);
            }
            #pragma unroll
            for (int u = 0; u < 8; u++) {
                if (sl[u] >= 0) {
                    acc.x += v[u].x; acc.y += v[u].y;
                    acc.z += v[u].z; acc.w += v[u].w;
                }
            }
        }
        atomicAdd(&gl[oq * 4 + 0], fmaxf(acc.x, 0.f));
        atomicAdd(&gl[oq * 4 + 1], fmaxf(acc.y, 0.f));
        atomicAdd(&gl[oq * 4 + 2], fmaxf(acc.z, 0.f));
        atomicAdd(&gl[oq * 4 + 3], fmaxf(acc.w, 0.f));
    }
    __syncthreads();
    if (tid < FO) unsafeAtomicAdd(&g[tid], gl[tid]);
}

// ---------------------------------------------------------------------------
// D7: MLP head, 16 blocks, 2 inter-block barriers.
// ---------------------------------------------------------------------------
__global__ __launch_bounds__(256)
void mlp_kernel(const float* __restrict__ g, int* __restrict__ ctr,
                const float* __restrict__ Wd1, const float* __restrict__ bd1,
                const float* __restrict__ Wd2, const float* __restrict__ bd2,
                const float* __restrict__ Wd3, const float* __restrict__ bd3,
                const float* __restrict__ Wd4, const float* __restrict__ bd4,
                const float* __restrict__ Wd5, const float* __restrict__ bd5,
                const float* __restrict__ Wd6, const float* __restrict__ bd6,
                float* __restrict__ m3, float* __restrict__ m4,
                float* __restrict__ out)
{
    __shared__ float v0[768];
    __shared__ float v1[96];
    __shared__ float red[256];
    const int tid = threadIdx.x, b = blockIdx.x;

    if (tid < 24) v0[tid] = g[tid];
    __syncthreads();
    if (tid < 96) {
        float a = bd1[tid];
        #pragma unroll
        for (int i = 0; i < 24; i++) a = fmaf(v0[i], Wd1[i * 96 + tid], a);
        v1[tid] = fmaxf(a, 0.f);
    }
    __syncthreads();
    {
        float a = bd2[tid];
        #pragma unroll
        for (int i = 0; i < 96; i++) a = fmaf(v1[i], Wd2[i * 256 + tid], a);
        red[tid] = fmaxf(a, 0.f);
    }
    __syncthreads();
    v0[tid] = red[tid];
    __syncthreads();

    if (tid < 192) {
        const int o = b * 48 + (tid % 48), kg = tid / 48;
        float a = 0.f;
        #pragma unroll 8
        for (int i = kg * 64; i < kg * 64 + 64; i++)
            a = fmaf(v0[i], Wd3[(size_t)i * 768 + o], a);
        red[tid] = a;
    }
    __syncthreads();
    if (tid < 48) {
        float s = bd3[b * 48 + tid] + red[tid] + red[48 + tid] + red[96 + tid] + red[144 + tid];
        gstore(&m3[b * 48 + tid], fmaxf(s, 0.f));
    }
    mbarrier(ctr, 1 * NBM, true);

    for (int i = tid; i < 768; i += 256) v0[i] = gload(&m3[i]);
    __syncthreads();
    {
        const int o = b * 32 + (tid & 31), kg = tid >> 5;
        float a = 0.f;
        #pragma unroll 8
        for (int i = kg * 96; i < kg * 96 + 96; i++)
            a = fmaf(v0[i], Wd4[(size_t)i * 512 + o], a);
        red[tid] = a;
    }
    __syncthreads();
    if (tid < 32) {
        float s = bd4[b * 32 + tid];
        #pragma unroll
        for (int k = 0; k < 8; k++) s += red[k * 32 + tid];
        gstore(&m4[b * 32 + tid], fmaxf(s, 0.f));
    }
    mbarrier(ctr, 2 * NBM, b == 0);

    if (b == 0) {
        for (int i = tid; i < 512; i += 256) v0[i] = gload(&m4[i]);
        __syncthreads();
        {
            const int o = tid & 63, kg = tid >> 6;
            float a = 0.f;
            #pragma unroll 8
            for (int i = kg * 128; i < kg * 128 + 128; i++)
                a = fmaf(v0[i], Wd5[(size_t)i * 64 + o], a);
            red[tid] = a;
        }
        __syncthreads();
        if (tid < 64) {
            float s = bd5[tid] + red[tid] + red[64 + tid] + red[128 + tid] + red[192 + tid];
            float v = fmaxf(s, 0.f) * Wd6[tid];
            #pragma unroll
            for (int off = 32; off > 0; off >>= 1)
                v += __shfl_down(v, off, 64);
            if (tid == 0) out[0] = v + bd6[0];
        }
    }
}

// ---------------------------------------------------------------------------
extern "C" void kernel_launch(void* const* d_in, const int* in_sizes, int n_in,
                              void* d_out, int out_size, void* d_ws, size_t ws_size,
                              hipStream_t stream)
{
    const float* x     = (const float*)d_in[0];
    const int*   eidx  = (const int*)  d_in[1];
    const float* e     = (const float*)d_in[2];
    const float* We1   = (const float*)d_in[3];  const float* be1 = (const float*)d_in[4];
    const float* root1 = (const float*)d_in[5];  const float* b1  = (const float*)d_in[6];
    const float* We2   = (const float*)d_in[7];  const float* be2 = (const float*)d_in[8];
    const float* root2 = (const float*)d_in[9];  const float* b2  = (const float*)d_in[10];
    const float* We3   = (const float*)d_in[11]; const float* be3 = (const float*)d_in[12];
    const float* root3 = (const float*)d_in[13]; const float* b3  = (const float*)d_in[14];
    const float* Wd1 = (const float*)d_in[15]; const float* bd1 = (const float*)d_in[16];
    const float* Wd2 = (const float*)d_in[17]; const float* bd2 = (const float*)d_in[18];
    const float* Wd3 = (const float*)d_in[19]; const float* bd3 = (const float*)d_in[20];
    const float* Wd4 = (const float*)d_in[21]; const float* bd4 = (const float*)d_in[22];
    const float* Wd5 = (const float*)d_in[23]; const float* bd5 = (const float*)d_in[24];
    const float* Wd6 = (const float*)d_in[25]; const float* bd6 = (const float*)d_in[26];

    // ---- workspace layout (4-byte units) ----
    int*   wi      = (int*)d_ws;
    float* wf      = (float*)d_ws;
    int*   cnt_s   = wi;                       //         0 ..    20000
    int*   cnt_t   = wi + 20000;               //     20000 ..    40000
    float* g       = wf + 40000;               //     24
    int*   mctr    = wi + 40064;               //     own 64B line
    float* m3      = wf + 40096;               //     768
    float* m4      = m3 + 768;                 //     512   (ends 41376)
    int*   te_slot = wi + 41376;               //     640,000 ->   681,376
    float* esort   = wf + 681376;              //     640,000*8 = 5,120,000 -> 5,801,376
    float* seg9_1  = wf + 5801376;             //     800,000 -> 6,601,376
    float* seg9_2  = wf + 6601376;             //     480,000 -> 7,081,376
    float* seg9_3  = wf + 7081376;             //     480,000 -> 7,561,376
    float* msg1    = wf + 7561376;             //     25,600,000 -> 33,161,376
    float* msg3    = msg1;                     //     msg1 dead before msg3 written
    float* msg2    = wf + 33161376;            //     15,360,000 -> 48,521,376
    // total ~48.5M floats ~= 194 MB

    // D1: zero cnt_s + cnt_t + g + mctr + m3/m4 (165 KB)
    hipMemsetAsync(d_ws, 0, (size_t)41376 * sizeof(float), stream);

    // D2: dual buckets + esort (e rows in src-slot order)
    bucket_kernel<<<625, 256, 0, stream>>>(eidx, e, cnt_s, cnt_t, te_slot, esort);

    // D3: layer 1 — x -> P1(LDS) -> msg1 + seg9_1
    l1_push_kernel<<<NN / TN2, 256, 0, stream>>>(x, We1, be1, root1, b1,
                                                 cnt_s, esort, seg9_1, msg1);

    // D4: gather msg1 -> h1 -> P2(LDS) -> msg2 + seg9_2   (2 W passes)
    gather_gemm_push_kernel<40, 24, 30><<<NN / TN2, 256, 0, stream>>>(
        msg1, cnt_t, te_slot, seg9_1, We2, be2, root2, b2,
        cnt_s, esort, seg9_2, msg2);

    // D5: gather msg2 -> h2 -> P3(LDS) -> msg3 + seg9_3   (1 W pass)
    gather_gemm_push_kernel<24, 24, 60><<<NN / TN2, 256, 0, stream>>>(
        msg2, cnt_t, te_slot, seg9_2, We3, be3, root3, b3,
        cnt_s, esort, seg9_3, msg3);

    // D6: g = colsum(relu(msg3-sum + seg9_3))
    msg_colsum_kernel<<<NN / TN2, 256, 0, stream>>>(msg3, cnt_t, te_slot, seg9_3, g);

    // D7: MLP head (16 blocks, 2 internal barriers)
    mlp_kernel<<<NBM, 256, 0, stream>>>(g, mctr,
                                        Wd1, bd1, Wd2, bd2, Wd3, bd3,
                                        Wd4, bd4, Wd5, bd5, Wd6, bd6,
                                        m3, m4, (float*)d_out);
}